// Round 7
// baseline (150.531 us; speedup 1.0000x reference)
//
#include <hip/hip_runtime.h>

typedef __attribute__((ext_vector_type(8))) short short8;
typedef __attribute__((ext_vector_type(16))) float f32x16;

// ws layout:
//   Ft2  [z=512][yy=66][xx=66][8] bf16 halo-padded features, z = c*8 + b   (35.68 MB)
//   wt2  [slab=72][e=8][n=128][8] bf16 B slabs, e = i&7 (chunk-major)      (1.18 MB)
#define FT2_SHORTS (512u * 4356u * 8u)
#define PLANE16    4356

typedef __attribute__((address_space(3))) unsigned int lds_u32_t;
typedef __attribute__((address_space(1))) const unsigned int g_u32_t;

__device__ __forceinline__ unsigned short f2bf(float x) {
    union { float f; unsigned u; } v; v.f = x;
    unsigned r = v.u + 0x7FFFu + ((v.u >> 16) & 1u);   // RNE bf16
    return (unsigned short)(r >> 16);
}

__device__ __forceinline__ void feat8(float p, unsigned short* uf) {
    float e   = __expf(-p);
    float sig = 1.f / (1.f + e);
    uf[0] = f2bf(p * sig);
    float u  = p * 1.5f + 4.5f;
    float fj = floorf(u);
    int   j0 = (int)fj;
    float t  = u - fj;
    bool  inr = (u >= 0.f) && (u < 9.f);
    float t2 = t * t, t3 = t2 * t;
    const float c16 = 1.f / 6.f;
    float r0 = t3 * c16;
    float r1 = (-3.f * t3 + 3.f * t2 + 3.f * t + 1.f) * c16;
    float r2 = (3.f * t3 - 6.f * t2 + 4.f) * c16;
    float s1 = 1.f - t;
    float r3 = s1 * s1 * s1 * c16;
#pragma unroll
    for (int g = 0; g < 6; ++g) {
        int r = j0 - g;
        float v = (r == 0) ? r0 : ((r == 1) ? r1 : ((r == 2) ? r2 : ((r == 3) ? r3 : 0.f)));
        uf[1 + g] = f2bf(inr ? v : 0.f);
    }
    uf[7] = 0;
}

// ---- Fused prep: per block (512): 144 B-chunks + 1 halo plane + 1 feature line ----
__global__ __launch_bounds__(256)
void prep_all(const float* __restrict__ x,
              const float* __restrict__ bw, const float* __restrict__ sw,
              unsigned short* __restrict__ ft, unsigned short* __restrict__ wt) {
    const int blk = blockIdx.x;          // 0..511
    const int tid = threadIdx.x;

    // (1) B prep into slab-chunk-major layout: wt[slab][i&7][n][8]
    if (tid < 144) {
        int idx = blk * 144 + tid;
        int o = idx / 576;
        int i = idx - o * 576;
        int slab = i >> 3, e = i & 7;
        union { unsigned short u[8]; uint4 v; } pk;
        pk.u[0] = f2bf(bw[o * 576 + i]);
        const float* s = sw + (size_t)(o * 576 + i) * 6;
#pragma unroll
        for (int f = 0; f < 6; ++f) pk.u[1 + f] = f2bf(s[f]);
        pk.u[7] = 0;
        *(uint4*)(wt + ((size_t)slab * 8192 + e * 1024 + o * 8)) = pk.v;
    }

    // (2) halo plane z = blk: feat8(0) into the 260 border cells
    {
        short8 pad = { 0, 0, (short)0x3CAB, (short)0x3EF5,
                       (short)0x3EF5, (short)0x3CAB, 0, 0 };
        for (int t = tid; t < 260; t += 256) {
            int yy, xx;
            if (t < 66)       { yy = 0;       xx = t; }
            else if (t < 132) { yy = 65;      xx = t - 66; }
            else if (t < 196) { yy = t - 131; xx = 0; }
            else              { yy = t - 195; xx = 65; }
            ((short8*)ft)[blk * PLANE16 + yy * 66 + xx] = pad;
        }
    }

    // (3) features for line = blk (b = blk>>6, y = blk&63)
    __shared__ float Xl[64 * 65];
    const int b = blk >> 6, y = blk & 63;
    const float* xl = x + (size_t)blk * 4096;
    for (int f4 = tid; f4 < 1024; f4 += 256) {
        float4 v = ((const float4*)xl)[f4];
        int xx = f4 >> 4, c4 = (f4 & 15) << 2;
        float* d = &Xl[xx * 65 + c4];
        d[0] = v.x; d[1] = v.y; d[2] = v.z; d[3] = v.w;
    }
    __syncthreads();
    const int xx = tid & 63;
    const int cw = tid >> 6;
#pragma unroll 4
    for (int p = 0; p < 16; ++p) {
        int c = cw + (p << 2);
        float pv = Xl[xx * 65 + c];
        union { unsigned short u[8]; uint4 v; } pk;
        feat8(pv, pk.u);
        size_t o16 = (size_t)(c * 8 + b) * PLANE16 + (y + 1) * 66 + (xx + 1);
        *(uint4*)(ft + (o16 << 3)) = pk.v;
    }
}

// ---- Main GEMM: tile 128m(2 lines) x 128n, K-split 2, grid 512, block 512 ----
// 2 blocks/CU (48 KB LDS each), XCD swizzle (b = blk&7 -> XCD owns one image).
// 72 HALF-SLAB phases per block (K=64 each): staging only 16 KB/phase
// (B 8 KB + A 8 KB) = 2 loads/thread uniform -> steady vmcnt(4); triple-buffer
// 3 x 16 KB. Waves (kq,mh,nh): kq picks the K16-pair {2kq+h}, mh = line,
// nh = n-half; wave tile 64m x 64n, 4 accs, 4 ds_read + 4 MFMA per phase,
// straight-line with precomputed offsets. Epilogue: one-round kq-reduction
// in LDS (2 sub-rounds of 32 KB), then f32 atomicAdd (proven ~free, R0/R1).
#define BUF_SHORTS 8192

#define STAGE(hs, q_)                                                                 \
    {                                                                                 \
        unsigned short* bufq = Bufs + (q_) * BUF_SHORTS;                              \
        const unsigned short* bsrc = wt + (size_t)(kk72 + (hs)) * 4096;               \
        _Pragma("unroll")                                                             \
        for (int t = 0; t < 2; ++t) {                                                 \
            int u = wave * 2 + t;            /* 0..15: u<8 = B, u>=8 = A */           \
            if (u < 8) {                                                              \
                int boff = u * 512 + lane * 8;                                        \
                __builtin_amdgcn_global_load_lds((g_u32_t*)(bsrc + boff),             \
                                                 (lds_u32_t*)(bufq + boff), 16, 0, 0);\
            } else {                                                                  \
                int ua  = u - 8;             /* chunk*2 + ln, 0..7 */                 \
                int ia  = (kk72 + (hs)) * 4 + (ua >> 1);                              \
                int ln  = ua & 1;                                                     \
                int c_  = (ia * 7282) >> 16;                                          \
                int i9_ = ia - c_ * 9;                                                \
                int kh_ = (i9_ * 11) >> 5;                                            \
                int kw_ = i9_ - kh_ * 3;                                              \
                const unsigned short* asrc = ft +                                     \
                    (((size_t)(c_ * 8 + b) * PLANE16 + (y0 + ln + kh_) * 66 + kw_)    \
                     << 3) + lane * 8;                                                \
                unsigned short* adst = bufq + 4096 + ua * 512 + lane * 8;             \
                __builtin_amdgcn_global_load_lds((g_u32_t*)asrc, (lds_u32_t*)adst,    \
                                                 16, 0, 0);                           \
            }                                                                         \
        }                                                                             \
    }

#define COMPUTE(q_)                                                                   \
    {                                                                                 \
        const unsigned short* bufr = Bufs + (q_) * BUF_SHORTS;                        \
        short8 a0 = *(const short8*)(bufr + aoff);                                    \
        short8 a1 = *(const short8*)(bufr + aoff + 256);                              \
        short8 b0 = *(const short8*)(bufr + boff);                                    \
        short8 b1 = *(const short8*)(bufr + boff + 256);                              \
        acc00 = __builtin_amdgcn_mfma_f32_32x32x16_bf16(a0, b0, acc00, 0, 0, 0);      \
        acc01 = __builtin_amdgcn_mfma_f32_32x32x16_bf16(a0, b1, acc01, 0, 0, 0);      \
        acc10 = __builtin_amdgcn_mfma_f32_32x32x16_bf16(a1, b0, acc10, 0, 0, 0);      \
        acc11 = __builtin_amdgcn_mfma_f32_32x32x16_bf16(a1, b1, acc11, 0, 0, 0);      \
    }

#define PHASE(q_, n_, stagehs, dostage_)                                              \
    {                                                                                 \
        asm volatile("s_waitcnt vmcnt(" #n_ ")" ::: "memory");                        \
        __builtin_amdgcn_s_barrier();                                                 \
        asm volatile("" ::: "memory");                                                \
        __builtin_amdgcn_s_setprio(1);                                                \
        COMPUTE(q_)                                                                   \
        __builtin_amdgcn_s_setprio(0);                                                \
        asm volatile("" ::: "memory");                                                \
        __builtin_amdgcn_s_barrier();                                                 \
        asm volatile("" ::: "memory");                                                \
        if (dostage_) STAGE(stagehs, q_);                                             \
    }

// Epilogue reduce helpers: conflict-free float4 layout (lane-stride 16 B).
#define DUMPA(base_, A_)                                                              \
    {   float4* s4 = (float4*)(red + (base_));                                        \
        _Pragma("unroll")                                                             \
        for (int c = 0; c < 4; ++c)                                                   \
            s4[c * 64 + lane] = make_float4(A_[4*c], A_[4*c+1], A_[4*c+2], A_[4*c+3]); }
#define ADDA(base_, A_)                                                               \
    {   const float4* s4 = (const float4*)(red + (base_));                            \
        _Pragma("unroll")                                                             \
        for (int c = 0; c < 4; ++c) {                                                 \
            float4 rv = s4[c * 64 + lane];                                            \
            A_[4*c] += rv.x; A_[4*c+1] += rv.y; A_[4*c+2] += rv.z; A_[4*c+3] += rv.w; } }

__global__ __launch_bounds__(512, 4)
void convkan_gemm(const unsigned short* __restrict__ ft,
                  const unsigned short* __restrict__ wt,
                  const float* __restrict__ bias,
                  float* __restrict__ out) {
    extern __shared__ unsigned short Bufs[];     // 3 x 8192 shorts = 48 KB

    const int tid  = threadIdx.x;
    const int blk  = blockIdx.x;                 // 0..511
    const int kk   = blk >> 8;                   // K-half
    const int mbr  = blk & 255;
    const int mb   = ((mbr & 7) << 5) | (mbr >> 3);  // XCD swizzle: XCD owns image
    const int lane = tid & 63;
    const int wave = tid >> 6;                   // 0..7
    const int kq   = wave >> 2;                  // K16-pair within half-slab (0..1)
    const int mh   = (wave >> 1) & 1;            // line within tile
    const int nh   = wave & 1;                   // n-half (64 ch)
    const int l32  = lane & 31;
    const int h    = lane >> 5;                  // k-half within MFMA K16

    const int b  = mb >> 5;                      // image 0..7
    const int y0 = (mb & 31) << 1;               // first of 2 lines
    const int kk72 = kk * 72;                    // half-slab base

    const int eloc = (kq << 1) + h;              // chunk 0..3 within half-slab
    const int aoff = 4096 + eloc * 1024 + mh * 512 + l32 * 8;
    const int boff = eloc * 1024 + nh * 512 + l32 * 8;

    f32x16 acc00, acc01, acc10, acc11;
#pragma unroll
    for (int e = 0; e < 16; ++e) { acc00[e] = 0.f; acc01[e] = 0.f; acc10[e] = 0.f; acc11[e] = 0.f; }

    // prologue: fill the 3-deep pipeline (half-slabs 0,1,2)
    STAGE(0, 0);
    STAGE(1, 1);
    STAGE(2, 2);

    // steady state: phases 0..68 stage half-slabs 3..71
    for (int it3 = 0; it3 < 23; ++it3) {
        const int it = it3 * 3;
        PHASE(0, 4, it + 3, true)
        PHASE(1, 4, it + 4, true)
        PHASE(2, 4, it + 5, true)
    }
    // tail: phases 69, 70, 71 — drain pipeline
    PHASE(0, 4, 0, false)
    PHASE(1, 2, 0, false)
    PHASE(2, 0, 0, false)

    // ---- kq-reduction (2 sub-rounds of 32 KB in LDS), then atomic store ----
    __syncthreads();
    float* red = (float*)Bufs;
    const int grp = mh * 2 + nh;                 // 0..3

    if (kq == 1) { DUMPA(grp * 2048,        acc00);
                   DUMPA(grp * 2048 + 1024, acc01); }
    __syncthreads();
    if (kq == 0) { ADDA(grp * 2048,        acc00);
                   ADDA(grp * 2048 + 1024, acc01); }
    __syncthreads();
    if (kq == 1) { DUMPA(grp * 2048,        acc10);
                   DUMPA(grp * 2048 + 1024, acc11); }
    __syncthreads();
    if (kq == 0) {
        ADDA(grp * 2048,        acc10);
        ADDA(grp * 2048 + 1024, acc11);

        const int ncol = nh * 64 + l32;
        const float bv0 = kk ? 0.f : bias[ncol];
        const float bv1 = kk ? 0.f : bias[ncol + 32];
        const int prow = mb * 128 + mh * 64;     // line mh of the 2-line tile
#pragma unroll
        for (int r = 0; r < 16; ++r) {
            int mrow = (r & 3) + ((r >> 2) << 3) + 4 * h;
            float* p = out + (size_t)(prow + mrow) * 128 + ncol;
            atomicAdd(p,      acc00[r] + bv0);
            atomicAdd(p + 32, acc01[r] + bv1);
            float* p2 = out + (size_t)(prow + 32 + mrow) * 128 + ncol;
            atomicAdd(p2,      acc10[r] + bv0);
            atomicAdd(p2 + 32, acc11[r] + bv1);
        }
    }
}

extern "C" void kernel_launch(void* const* d_in, const int* in_sizes, int n_in,
                              void* d_out, int out_size, void* d_ws, size_t ws_size,
                              hipStream_t stream) {
    (void)in_sizes; (void)n_in; (void)ws_size;
    const float* x        = (const float*)d_in[0];
    const float* base_w   = (const float*)d_in[1];
    const float* spline_w = (const float*)d_in[2];
    const float* bias     = (const float*)d_in[3];
    float* out = (float*)d_out;

    unsigned short* ft = (unsigned short*)d_ws;      // 35.68 MB halo features
    unsigned short* wt = ft + FT2_SHORTS;            // 1.18 MB tiled B (slab-major)

    hipMemsetAsync(out, 0, (size_t)out_size * sizeof(float), stream);
    hipLaunchKernelGGL(prep_all, dim3(512), dim3(256), 0, stream,
                       x, base_w, spline_w, ft, wt);

    const int shmem = 3 * BUF_SHORTS * 2;            // 48 KB -> 2 blocks/CU
    (void)hipFuncSetAttribute((const void*)convkan_gemm,
                              hipFuncAttributeMaxDynamicSharedMemorySize, shmem);
    hipLaunchKernelGGL(convkan_gemm, dim3(512), dim3(512), shmem, stream,
                       ft, wt, bias, out);
}